// Round 7
// baseline (218.215 us; speedup 1.0000x reference)
//
#include <hip/hip_runtime.h>
#include <math.h>

#define HEADS 6
#define SEQ   2048
#define DIM   768
#define HDIM  128
#define BATCH 4
#define MTOT  (BATCH*SEQ)   // 8192
#define NKV   (SEQ/32)      // 64

typedef float  f32x4   __attribute__((ext_vector_type(4)));
typedef float  f32x16  __attribute__((ext_vector_type(16)));
typedef __bf16 bf16x8  __attribute__((ext_vector_type(8)));
typedef __bf16 bf16x4  __attribute__((ext_vector_type(4)));
typedef float  f32x4v  __attribute__((ext_vector_type(4)));

typedef __attribute__((address_space(3))) void lds_v;
typedef __attribute__((address_space(1))) void gbl_v;

__device__ __forceinline__ f32x4 mfma16(bf16x8 a, bf16x8 b, f32x4 c) {
    return __builtin_amdgcn_mfma_f32_16x16x32_bf16(a, b, c, 0, 0, 0);
}
__device__ __forceinline__ f32x16 mfma32(bf16x8 a, bf16x8 b, f32x16 c) {
    return __builtin_amdgcn_mfma_f32_32x32x16_bf16(a, b, c, 0, 0, 0);
}
__device__ __forceinline__ unsigned int cvtpk(float lo, float hi) {
    unsigned int r;
    asm("v_cvt_pk_bf16_f32 %0, %1, %2" : "=v"(r) : "v"(lo), "v"(hi));
    return r;
}

// ---------------- cast x (f32 -> bf16) ----------------
__global__ __launch_bounds__(256) void cast_x_kernel(const float* __restrict__ x,
                                                     __bf16* __restrict__ xb) {
    int i = (blockIdx.x * 256 + threadIdx.x) * 4;
    f32x4v v = *(const f32x4v*)(x + i);
    bf16x4 o;
    o[0] = (__bf16)v[0]; o[1] = (__bf16)v[1];
    o[2] = (__bf16)v[2]; o[3] = (__bf16)v[3];
    *(bf16x4*)(xb + i) = o;
}

// ---------------- transpose weights W[k][n] f32 -> Wt[n][k] bf16 ----------------
__global__ __launch_bounds__(256) void transpose_w_kernel(
    const float* __restrict__ W0, const float* __restrict__ W1,
    const float* __restrict__ W2, const float* __restrict__ W3,
    __bf16* __restrict__ T0, __bf16* __restrict__ T1,
    __bf16* __restrict__ T2, __bf16* __restrict__ T3) {
    __shared__ float tile[32][33];
    const float* W; __bf16* T;
    if      (blockIdx.z == 0) { W = W0; T = T0; }
    else if (blockIdx.z == 1) { W = W1; T = T1; }
    else if (blockIdx.z == 2) { W = W2; T = T2; }
    else                      { W = W3; T = T3; }
    int n0 = blockIdx.x * 32, k0 = blockIdx.y * 32;
    int tx = threadIdx.x & 31, ty = threadIdx.x >> 5;
#pragma unroll
    for (int i = 0; i < 4; ++i)
        tile[ty + i*8][tx] = W[(size_t)(k0 + ty + i*8) * DIM + n0 + tx];
    __syncthreads();
#pragma unroll
    for (int i = 0; i < 4; ++i)
        T[(size_t)(n0 + ty + i*8) * DIM + k0 + tx] = (__bf16)tile[tx][ty + i*8];
}

// ============ GEMM core: triple-buffered LDS, 2-ahead prefetch, vmcnt(4) ============
#define GEMM_PIPE(A_PTR, B_PTR, NKSTEP)                                           \
    __shared__ __align__(16) __bf16 As[3][128 * 32];                              \
    __shared__ __align__(16) __bf16 Bs[3][128 * 32];                              \
    const int tid  = threadIdx.x;                                                 \
    const int wave = tid >> 6, lane = tid & 63;                                   \
    const int l16  = lane & 15, lh = lane >> 4;                                   \
    const int wr = wave >> 1, wc = wave & 1;                                      \
    f32x4 acc[4][4] = {};                                                         \
    auto stage = [&](int buf, int step) {                                         \
        const int k0 = step * 32;                                                 \
        _Pragma("unroll")                                                         \
        for (int ci = 0; ci < 4; ++ci) {                                          \
            int c = wave * 4 + ci;                                                \
            int t = c & 7;                                                        \
            int e = (t * 64 + lane) * 8;                                          \
            int r = e >> 5, kk = e & 31;                                          \
            const __bf16* gp = (c < 8) ? ((A_PTR) + (size_t)(m0 + r) * DIM + k0 + kk) \
                                       : ((B_PTR) + (size_t)(n0 + r) * DIM + k0 + kk); \
            __bf16* lp = (c < 8 ? As[buf] : Bs[buf]) + t * 512;                   \
            __builtin_amdgcn_global_load_lds((const gbl_v*)gp, (lds_v*)lp, 16, 0, 0); \
        }                                                                         \
    };                                                                            \
    stage(0, 0); stage(1, 1);                                                     \
    asm volatile("s_waitcnt vmcnt(4)" ::: "memory");                              \
    __builtin_amdgcn_s_barrier();                                                 \
    for (int t = 0; t < (NKSTEP); ++t) {                                          \
        const int cur = t % 3;                                                    \
        if (t + 2 < (NKSTEP)) stage((t + 2) % 3, t + 2);                          \
        bf16x8 af[4], bfr[4];                                                     \
        _Pragma("unroll")                                                         \
        for (int i = 0; i < 4; ++i)                                               \
            af[i] = *(const bf16x8*)&As[cur][(wr*64 + i*16 + l16) * 32 + lh*8];   \
        _Pragma("unroll")                                                         \
        for (int j = 0; j < 4; ++j)                                               \
            bfr[j] = *(const bf16x8*)&Bs[cur][(wc*64 + j*16 + l16) * 32 + lh*8];  \
        __builtin_amdgcn_s_setprio(1);                                            \
        _Pragma("unroll")                                                         \
        for (int i = 0; i < 4; ++i)                                               \
            _Pragma("unroll")                                                     \
            for (int j = 0; j < 4; ++j)                                           \
                acc[i][j] = mfma16(af[i], bfr[j], acc[i][j]);                     \
        __builtin_amdgcn_s_setprio(0);                                            \
        if (t + 2 < (NKSTEP))      asm volatile("s_waitcnt vmcnt(4)" ::: "memory"); \
        else if (t + 1 < (NKSTEP)) asm volatile("s_waitcnt vmcnt(0)" ::: "memory"); \
        __builtin_amdgcn_s_barrier();                                             \
    }

// ---------------- fused QKV GEMM: [8192,768] @ Wcat[2304,768]^T ----------------
__global__ __launch_bounds__(256) void gemm_qkv(const __bf16* __restrict__ A,
                                                const __bf16* __restrict__ Wcat,
                                                const float* __restrict__ bq,
                                                const float* __restrict__ bk,
                                                const float* __restrict__ bv,
                                                __bf16* __restrict__ Qb,
                                                __bf16* __restrict__ Kb,
                                                __bf16* __restrict__ Vt) {
    const int bn = blockIdx.x % (2304 / 128), bm = blockIdx.x / (2304 / 128);
    const int m0 = bm * 128, n0 = bn * 128;
    GEMM_PIPE(A, Wcat, 24)

    const int sel = n0 / DIM;                 // 0=Q 1=K 2=V (block-uniform)
    const float* bias = sel == 0 ? bq : (sel == 1 ? bk : bv);
#pragma unroll
    for (int i = 0; i < 4; ++i) {
        int row = m0 + wr*64 + i*16 + lh*4;
#pragma unroll
        for (int j = 0; j < 4; ++j) {
            int col  = n0 + wc*64 + j*16 + l16;
            int lcol = col - sel * DIM;
            float bvv = bias[lcol];
            if (sel < 2) {
                __bf16* o = (sel == 0) ? Qb : Kb;
#pragma unroll
                for (int r = 0; r < 4; ++r)
                    o[(size_t)(row + r) * DIM + lcol] = (__bf16)(acc[i][j][r] + bvv);
            } else {
                int bb = row >> 11, ll = row & (SEQ - 1);
                int hh = lcol >> 7, dd = lcol & (HDIM - 1);
                bf16x4 pk;
#pragma unroll
                for (int r = 0; r < 4; ++r) pk[r] = (__bf16)(acc[i][j][r] + bvv);
                *(bf16x4*)&Vt[((size_t)((bb*HEADS + hh) * HDIM + dd)) * SEQ + ll] = pk;
            }
        }
    }
}

// ---------------- out-proj GEMM: [8192,768] @ Wto[768,768]^T -> f32 ----------------
__global__ __launch_bounds__(256) void gemm_out(const __bf16* __restrict__ A,
                                                const __bf16* __restrict__ Bt,
                                                const float* __restrict__ bias,
                                                float* __restrict__ outp) {
    const int bn = blockIdx.x % (DIM / 128), bm = blockIdx.x / (DIM / 128);
    const int m0 = bm * 128, n0 = bn * 128;
    GEMM_PIPE(A, Bt, 24)

#pragma unroll
    for (int i = 0; i < 4; ++i) {
        int row = m0 + wr*64 + i*16 + lh*4;
#pragma unroll
        for (int j = 0; j < 4; ++j) {
            int col = n0 + wc*64 + j*16 + l16;
            float bv = bias[col];
#pragma unroll
            for (int r = 0; r < 4; ++r)
                outp[(size_t)(row + r) * DIM + col] = acc[i][j][r] + bv;
        }
    }
}

// ---------------- flash attention: 1 wave/block, 32 q-rows, no LDS, no barriers ----
// Swapped QK^T via mfma_32x32x16(K,Q): lane holds q=lane&31, keys in regs
// (key=(r&3)+8*(r>>2)+4*hi). K and V fragments read DIRECTLY from global
// (L2-resident via XCD pinning) -> zero LDS, zero barriers; waves fully
// independent, latency hidden by TLP (~12 waves/CU). Softmax in-register
// with defer-max; P -> PV B-frag via v_cvt_pk_bf16_f32 + permlane32_swap.
// PV = mfma(V-frag, P-frag) -> O^T. Causal mask: key <= q+1 (tril k=1).
__global__ __launch_bounds__(64, 3) void attn_kernel(
    const __bf16* __restrict__ Q, const __bf16* __restrict__ K,
    const __bf16* __restrict__ Vt,
    __bf16* __restrict__ po, float* __restrict__ pm, float* __restrict__ pl,
    __bf16* __restrict__ Ob, int ks) {
    const int lane = threadIdx.x;
    const int l32 = lane & 31, hi = lane >> 5;
    // grid: 8 xcd x 3 bh_l x (64 tl x ks)  -> bh pinned to XCD
    const int id  = blockIdx.x;
    const int xcd = id & 7;
    const int idx = id >> 3;
    const int bh_l = idx % 3, rem = idx / 3;
    const int c = rem % ks, tl = rem / ks;                      // tl 0..63
    const int tile = (tl & 1) ? (63 - (tl >> 1)) : (tl >> 1);   // heavy/light mix
    const int bh = xcd + 8 * bh_l;
    const int b = bh / HEADS, h = bh - b * HEADS;
    const int qw0 = tile * 32;                                  // wave's first q row
    const float qs = 0.12751674770951932f;  // 1/sqrt(128) * log2(e)

    // Q B-frags: col=q=lane&31, k = 8*hi + e, 8 chunks over D=128
    bf16x8 qfr[8];
    {
        const __bf16* qp = Q + (size_t)(b*SEQ + qw0 + l32) * DIM + h*HDIM + hi*8;
#pragma unroll
        for (int cc = 0; cc < 8; ++cc) {
            bf16x8 v = *(const bf16x8*)(qp + cc*16);
            bf16x8 sv;
#pragma unroll
            for (int e = 0; e < 8; ++e) sv[e] = (__bf16)((float)v[e] * qs);
            qfr[cc] = sv;
        }
    }

    const __bf16* kgb = K  + (size_t)(b*SEQ) * DIM + h*HDIM;
    const __bf16* vgb = Vt + (size_t)bh * HDIM * SEQ;

    f32x16 o[4] = {};                          // O^T accum: 4 d-blocks of 32
    float mx = -INFINITY, lsum = 0.f;
    const int nkb = min(tile + 2, NKV);
    const int cnt = (nkb - c + ks - 1) / ks;

    for (int i = 0; i < cnt; ++i) {
        const int kb = c + i * ks;
        const int kbase = kb * 32;
        // K A-frags direct from L2: row=key=kbase+l32, k=8hi+e
        bf16x8 kf[8];
        const __bf16* kp = kgb + (size_t)(kbase + l32) * DIM + hi*8;
#pragma unroll
        for (int cc = 0; cc < 8; ++cc) kf[cc] = *(const bf16x8*)(kp + cc*16);
        f32x16 s = {};
        __builtin_amdgcn_s_setprio(1);
#pragma unroll
        for (int cc = 0; cc < 8; ++cc) s = mfma32(kf[cc], qfr[cc], s);
        __builtin_amdgcn_s_setprio(0);
        // V A-frags: row=d=db*32+l32, k-chunk kc; issue early (L2-resident)
        bf16x8 vf[8];
#pragma unroll
        for (int db = 0; db < 4; ++db)
#pragma unroll
            for (int kc = 0; kc < 2; ++kc)
                vf[db*2 + kc] = *(const bf16x8*)(vgb +
                    (size_t)(db*32 + l32) * SEQ + kbase + kc*16 + hi*8);

        float p[16];
#pragma unroll
        for (int r = 0; r < 16; ++r) p[r] = s[r];
        if (kbase + 30 > qw0) {            // diagonal: apply causal mask
            const int q1 = qw0 + l32 + 1;
#pragma unroll
            for (int r = 0; r < 16; ++r) {
                const int key = kbase + (r & 3) + 8*(r >> 2) + 4*hi;
                if (key > q1) p[r] = -INFINITY;
            }
        }
        float m0 = p[0];
#pragma unroll
        for (int r = 1; r < 16; ++r) m0 = fmaxf(m0, p[r]);
        m0 = fmaxf(m0, __shfl_xor(m0, 32));
        // defer-max: skip rescale while growth <= 8 (log2 domain)
        const bool defer = __all(m0 <= mx + 8.f && mx > -3e38f);
        if (!defer) {
            const float mnew = fmaxf(mx, m0);
            const float resc = (mx < mnew) ? exp2f(mx - mnew) : 1.0f;
            lsum *= resc;
#pragma unroll
            for (int db = 0; db < 4; ++db)
#pragma unroll
                for (int r = 0; r < 16; ++r) o[db][r] *= resc;
            mx = mnew;
        }
        const float mref = (mx == -INFINITY) ? 0.f : mx;   // all-masked guard
#pragma unroll
        for (int r = 0; r < 16; ++r) p[r] = exp2f(p[r] - mref);
        float rs = 0.f;
#pragma unroll
        for (int r = 0; r < 16; ++r) rs += p[r];
        rs += __shfl_xor(rs, 32);
        lsum += rs;
        // P -> bf16 B-frags via cvt_pk + permlane32_swap
        union { unsigned int u[4]; bf16x8 v; } pw[2];
#pragma unroll
        for (int kc = 0; kc < 2; ++kc) {
            unsigned int X = cvtpk(p[8*kc + 0], p[8*kc + 1]);
            unsigned int Y = cvtpk(p[8*kc + 4], p[8*kc + 5]);
            asm("v_permlane32_swap_b32 %0, %1" : "+v"(X), "+v"(Y));
            unsigned int X2 = cvtpk(p[8*kc + 2], p[8*kc + 3]);
            unsigned int Y2 = cvtpk(p[8*kc + 6], p[8*kc + 7]);
            asm("v_permlane32_swap_b32 %0, %1" : "+v"(X2), "+v"(Y2));
            pw[kc].u[0] = X; pw[kc].u[1] = X2; pw[kc].u[2] = Y; pw[kc].u[3] = Y2;
        }
        __builtin_amdgcn_s_setprio(1);
#pragma unroll
        for (int db = 0; db < 4; ++db) {
            o[db] = mfma32(vf[db*2 + 0], pw[0].v, o[db]);
            o[db] = mfma32(vf[db*2 + 1], pw[1].v, o[db]);
        }
        __builtin_amdgcn_s_setprio(0);
    }

    // write-out: lane holds q = qw0+l32 (col), d = db*32 + (reg&3)+8*(reg>>2)+4*hi
    if (ks == 1) {
        const float inv = 1.0f / lsum;
        __bf16* op = Ob + (size_t)(b*SEQ + qw0 + l32) * DIM + h*HDIM + hi*4;
#pragma unroll
        for (int db = 0; db < 4; ++db)
#pragma unroll
            for (int g = 0; g < 4; ++g) {
                bf16x4 pk;
#pragma unroll
                for (int r = 0; r < 4; ++r) pk[r] = (__bf16)(o[db][g*4 + r] * inv);
                *(bf16x4*)(op + db*32 + g*8) = pk;
            }
    } else {
        const int pid = (bh * 64 + tile) * ks + c;
        __bf16* pop = po + ((size_t)pid * 32 + l32) * HDIM + hi*4;
#pragma unroll
        for (int db = 0; db < 4; ++db)
#pragma unroll
            for (int g = 0; g < 4; ++g) {
                bf16x4 pk;
#pragma unroll
                for (int r = 0; r < 4; ++r) pk[r] = (__bf16)o[db][g*4 + r];
                *(bf16x4*)(pop + db*32 + g*8) = pk;
            }
        if (hi == 0) {
            pm[(size_t)pid * 32 + l32] = mx;
            pl[(size_t)pid * 32 + l32] = lsum;
        }
    }
}

// ---------------- merge split-K partials (32-row chunks) ----------------
__global__ __launch_bounds__(128) void merge_kernel(const __bf16* __restrict__ po,
    const float* __restrict__ pm, const float* __restrict__ pl,
    __bf16* __restrict__ Ob, int ks) {
    const int id = blockIdx.x;             // bh*64 + tile
    const int bh = id >> 6, tile = id & 63;
    const int b = bh / HEADS, h = bh - b * HEADS;
    const int lq = threadIdx.x >> 2;       // 0..31
    const int d0 = (threadIdx.x & 3) * 32;
    const int pb = id * ks;
    float M = -INFINITY;
    for (int cc = 0; cc < ks; ++cc) M = fmaxf(M, pm[(size_t)(pb + cc) * 32 + lq]);
    float L = 0.f, w[2] = {0.f, 0.f};
    for (int cc = 0; cc < ks; ++cc) {
        w[cc] = exp2f(pm[(size_t)(pb + cc) * 32 + lq] - M);
        L += w[cc] * pl[(size_t)(pb + cc) * 32 + lq];
    }
    const float invL = 1.0f / L;
    __bf16* op = Ob + (size_t)(b*SEQ + tile*32 + lq) * DIM + h*HDIM;
#pragma unroll
    for (int d = 0; d < 32; d += 8) {
        float acc[8] = {};
        for (int cc = 0; cc < ks; ++cc) {
            bf16x8 v = *(const bf16x8*)&po[((size_t)(pb + cc) * 32 + lq) * HDIM + d0 + d];
            const float wc = w[cc];
#pragma unroll
            for (int e = 0; e < 8; ++e) acc[e] += wc * (float)v[e];
        }
        bf16x8 ov;
#pragma unroll
        for (int e = 0; e < 8; ++e) ov[e] = (__bf16)(acc[e] * invL);
        *(bf16x8*)(op + d0 + d) = ov;
    }
}

// ---------------- launch ----------------
extern "C" void kernel_launch(void* const* d_in, const int* in_sizes, int n_in,
                              void* d_out, int out_size, void* d_ws, size_t ws_size,
                              hipStream_t stream) {
    const float* x  = (const float*)d_in[0];
    const float* Wq = (const float*)d_in[1];
    const float* bq = (const float*)d_in[2];
    const float* Wk = (const float*)d_in[3];
    const float* bk = (const float*)d_in[4];
    const float* Wv = (const float*)d_in[5];
    const float* bv = (const float*)d_in[6];
    const float* Wo = (const float*)d_in[7];
    const float* bo = (const float*)d_in[8];

    char* p = (char*)d_ws;
    const size_t SZ_X = (size_t)MTOT * DIM * 2;        // 12.6 MB
    const size_t SZ_W = (size_t)DIM * DIM * 2;         // 1.18 MB
    __bf16* xb   = (__bf16*)p; p += SZ_X;
    __bf16* Wcat = (__bf16*)p; p += 3 * SZ_W;          // [2304][768]
    __bf16* Wto  = (__bf16*)p; p += SZ_W;
    __bf16* Qb   = (__bf16*)p; p += SZ_X;
    __bf16* Kb   = (__bf16*)p; p += SZ_X;
    __bf16* Vt   = (__bf16*)p; p += SZ_X;
    __bf16* Ob   = (__bf16*)p; p += SZ_X;

    const size_t base = (size_t)(p - (char*)d_ws);
    const size_t SZ_PO = (size_t)24 * 64 * 2 * 32 * HDIM * 2;  // 25.2 MB (ks=2)
    const size_t SZ_PM = (size_t)24 * 64 * 2 * 32 * 4;         // 0.39 MB
    const int ks = (ws_size >= base + SZ_PO + 2 * SZ_PM) ? 2 : 1;
    __bf16* po = (__bf16*)p;            p += SZ_PO;
    float*  pmv = (float*)p;            p += SZ_PM;
    float*  plv = (float*)p;

    cast_x_kernel<<<(MTOT * DIM) / 1024, 256, 0, stream>>>(x, xb);
    transpose_w_kernel<<<dim3(DIM/32, DIM/32, 4), 256, 0, stream>>>(
        Wq, Wk, Wv, Wo,
        Wcat, Wcat + (size_t)DIM*DIM, Wcat + (size_t)2*DIM*DIM, Wto);

    gemm_qkv<<<(MTOT/128) * (2304/128), 256, 0, stream>>>(xb, Wcat, bq, bk, bv, Qb, Kb, Vt);

    attn_kernel<<<8 * 3 * 64 * ks, 64, 0, stream>>>(Qb, Kb, Vt, po, pmv, plv, Ob, ks);
    if (ks == 2)
        merge_kernel<<<24 * 64, 128, 0, stream>>>(po, pmv, plv, Ob, ks);

    gemm_out<<<(MTOT/128) * (DIM/128), 256, 0, stream>>>(Ob, Wto, bo, (float*)d_out);
}

// Round 8
// 192.823 us; speedup vs baseline: 1.1317x; 1.1317x over previous
//
#include <hip/hip_runtime.h>
#include <math.h>

#define HEADS 6
#define SEQ   2048
#define DIM   768
#define HDIM  128
#define BATCH 4
#define MTOT  (BATCH*SEQ)   // 8192
#define NKV   (SEQ/32)      // 64

typedef float  f32x4   __attribute__((ext_vector_type(4)));
typedef float  f32x16  __attribute__((ext_vector_type(16)));
typedef __bf16 bf16x8  __attribute__((ext_vector_type(8)));
typedef __bf16 bf16x4  __attribute__((ext_vector_type(4)));
typedef float  f32x4v  __attribute__((ext_vector_type(4)));

typedef __attribute__((address_space(3))) void lds_v;
typedef __attribute__((address_space(1))) void gbl_v;

__device__ __forceinline__ f32x4 mfma16(bf16x8 a, bf16x8 b, f32x4 c) {
    return __builtin_amdgcn_mfma_f32_16x16x32_bf16(a, b, c, 0, 0, 0);
}
__device__ __forceinline__ f32x16 mfma32(bf16x8 a, bf16x8 b, f32x16 c) {
    return __builtin_amdgcn_mfma_f32_32x32x16_bf16(a, b, c, 0, 0, 0);
}
__device__ __forceinline__ unsigned int cvtpk(float lo, float hi) {
    unsigned int r;
    asm("v_cvt_pk_bf16_f32 %0, %1, %2" : "=v"(r) : "v"(lo), "v"(hi));
    return r;
}

// ---------------- cast x (f32 -> bf16) ----------------
__global__ __launch_bounds__(256) void cast_x_kernel(const float* __restrict__ x,
                                                     __bf16* __restrict__ xb) {
    int i = (blockIdx.x * 256 + threadIdx.x) * 4;
    f32x4v v = *(const f32x4v*)(x + i);
    bf16x4 o;
    o[0] = (__bf16)v[0]; o[1] = (__bf16)v[1];
    o[2] = (__bf16)v[2]; o[3] = (__bf16)v[3];
    *(bf16x4*)(xb + i) = o;
}

// ---------------- transpose weights W[k][n] f32 -> Wt[n][k] bf16 ----------------
__global__ __launch_bounds__(256) void transpose_w_kernel(
    const float* __restrict__ W0, const float* __restrict__ W1,
    const float* __restrict__ W2, const float* __restrict__ W3,
    __bf16* __restrict__ T0, __bf16* __restrict__ T1,
    __bf16* __restrict__ T2, __bf16* __restrict__ T3) {
    __shared__ float tile[32][33];
    const float* W; __bf16* T;
    if      (blockIdx.z == 0) { W = W0; T = T0; }
    else if (blockIdx.z == 1) { W = W1; T = T1; }
    else if (blockIdx.z == 2) { W = W2; T = T2; }
    else                      { W = W3; T = T3; }
    int n0 = blockIdx.x * 32, k0 = blockIdx.y * 32;
    int tx = threadIdx.x & 31, ty = threadIdx.x >> 5;
#pragma unroll
    for (int i = 0; i < 4; ++i)
        tile[ty + i*8][tx] = W[(size_t)(k0 + ty + i*8) * DIM + n0 + tx];
    __syncthreads();
#pragma unroll
    for (int i = 0; i < 4; ++i)
        T[(size_t)(n0 + ty + i*8) * DIM + k0 + tx] = (__bf16)tile[tx][ty + i*8];
}

// ============ GEMM core: triple-buffered LDS, 2-ahead prefetch, vmcnt(4) ============
#define GEMM_PIPE(A_PTR, B_PTR, NKSTEP)                                           \
    __shared__ __align__(16) __bf16 As[3][128 * 32];                              \
    __shared__ __align__(16) __bf16 Bs[3][128 * 32];                              \
    const int tid  = threadIdx.x;                                                 \
    const int wave = tid >> 6, lane = tid & 63;                                   \
    const int l16  = lane & 15, lh = lane >> 4;                                   \
    const int wr = wave >> 1, wc = wave & 1;                                      \
    f32x4 acc[4][4] = {};                                                         \
    auto stage = [&](int buf, int step) {                                         \
        const int k0 = step * 32;                                                 \
        _Pragma("unroll")                                                         \
        for (int ci = 0; ci < 4; ++ci) {                                          \
            int c = wave * 4 + ci;                                                \
            int t = c & 7;                                                        \
            int e = (t * 64 + lane) * 8;                                          \
            int r = e >> 5, kk = e & 31;                                          \
            const __bf16* gp = (c < 8) ? ((A_PTR) + (size_t)(m0 + r) * DIM + k0 + kk) \
                                       : ((B_PTR) + (size_t)(n0 + r) * DIM + k0 + kk); \
            __bf16* lp = (c < 8 ? As[buf] : Bs[buf]) + t * 512;                   \
            __builtin_amdgcn_global_load_lds((const gbl_v*)gp, (lds_v*)lp, 16, 0, 0); \
        }                                                                         \
    };                                                                            \
    stage(0, 0); stage(1, 1);                                                     \
    asm volatile("s_waitcnt vmcnt(4)" ::: "memory");                              \
    __builtin_amdgcn_s_barrier();                                                 \
    for (int t = 0; t < (NKSTEP); ++t) {                                          \
        const int cur = t % 3;                                                    \
        if (t + 2 < (NKSTEP)) stage((t + 2) % 3, t + 2);                          \
        bf16x8 af[4], bfr[4];                                                     \
        _Pragma("unroll")                                                         \
        for (int i = 0; i < 4; ++i)                                               \
            af[i] = *(const bf16x8*)&As[cur][(wr*64 + i*16 + l16) * 32 + lh*8];   \
        _Pragma("unroll")                                                         \
        for (int j = 0; j < 4; ++j)                                               \
            bfr[j] = *(const bf16x8*)&Bs[cur][(wc*64 + j*16 + l16) * 32 + lh*8];  \
        __builtin_amdgcn_s_setprio(1);                                            \
        _Pragma("unroll")                                                         \
        for (int i = 0; i < 4; ++i)                                               \
            _Pragma("unroll")                                                     \
            for (int j = 0; j < 4; ++j)                                           \
                acc[i][j] = mfma16(af[i], bfr[j], acc[i][j]);                     \
        __builtin_amdgcn_s_setprio(0);                                            \
        if (t + 2 < (NKSTEP))      asm volatile("s_waitcnt vmcnt(4)" ::: "memory"); \
        else if (t + 1 < (NKSTEP)) asm volatile("s_waitcnt vmcnt(0)" ::: "memory"); \
        __builtin_amdgcn_s_barrier();                                             \
    }

// ---------------- fused QKV GEMM: [8192,768] @ Wcat[2304,768]^T ----------------
__global__ __launch_bounds__(256) void gemm_qkv(const __bf16* __restrict__ A,
                                                const __bf16* __restrict__ Wcat,
                                                const float* __restrict__ bq,
                                                const float* __restrict__ bk,
                                                const float* __restrict__ bv,
                                                __bf16* __restrict__ Qb,
                                                __bf16* __restrict__ Kb,
                                                __bf16* __restrict__ Vt) {
    const int bn = blockIdx.x % (2304 / 128), bm = blockIdx.x / (2304 / 128);
    const int m0 = bm * 128, n0 = bn * 128;
    GEMM_PIPE(A, Wcat, 24)

    const int sel = n0 / DIM;                 // 0=Q 1=K 2=V (block-uniform)
    const float* bias = sel == 0 ? bq : (sel == 1 ? bk : bv);
#pragma unroll
    for (int i = 0; i < 4; ++i) {
        int row = m0 + wr*64 + i*16 + lh*4;
#pragma unroll
        for (int j = 0; j < 4; ++j) {
            int col  = n0 + wc*64 + j*16 + l16;
            int lcol = col - sel * DIM;
            float bvv = bias[lcol];
            if (sel < 2) {
                __bf16* o = (sel == 0) ? Qb : Kb;
#pragma unroll
                for (int r = 0; r < 4; ++r)
                    o[(size_t)(row + r) * DIM + lcol] = (__bf16)(acc[i][j][r] + bvv);
            } else {
                int bb = row >> 11, ll = row & (SEQ - 1);
                int hh = lcol >> 7, dd = lcol & (HDIM - 1);
                bf16x4 pk;
#pragma unroll
                for (int r = 0; r < 4; ++r) pk[r] = (__bf16)(acc[i][j][r] + bvv);
                *(bf16x4*)&Vt[((size_t)((bb*HEADS + hh) * HDIM + dd)) * SEQ + ll] = pk;
            }
        }
    }
}

// ---------------- out-proj GEMM: [8192,768] @ Wto[768,768]^T -> f32 ----------------
__global__ __launch_bounds__(256) void gemm_out(const __bf16* __restrict__ A,
                                                const __bf16* __restrict__ Bt,
                                                const float* __restrict__ bias,
                                                float* __restrict__ outp) {
    const int bn = blockIdx.x % (DIM / 128), bm = blockIdx.x / (DIM / 128);
    const int m0 = bm * 128, n0 = bn * 128;
    GEMM_PIPE(A, Bt, 24)

#pragma unroll
    for (int i = 0; i < 4; ++i) {
        int row = m0 + wr*64 + i*16 + lh*4;
#pragma unroll
        for (int j = 0; j < 4; ++j) {
            int col = n0 + wc*64 + j*16 + l16;
            float bv = bias[col];
#pragma unroll
            for (int r = 0; r < 4; ++r)
                outp[(size_t)(row + r) * DIM + col] = acc[i][j][r] + bv;
        }
    }
}

// ---------------- flash attention: 32x32 MFMA, 4 waves x 32 q, K+V LDS-staged ----
// Both K (32x128) and V (128x32) staged via coalesced global_load_lds (L2-BW
// optimal, shared by 4 waves). Triple-buffered, 1-ahead prefetch, ONE barrier
// per iter: {stage((i+1)%3); vmcnt(4); s_barrier; compute(i%3)}. Safety: buf
// (i+1)%3 last read at compute(i-2), finished by all waves before barrier(i-1);
// vmcnt-before-barrier publishes all stage(i) writes. Swapped QK^T 32x32;
// in-register softmax + defer-max; P via cvt_pk+permlane32_swap; PV -> O^T.
// Causal mask: key <= q+1 (tril k=1).
__global__ __launch_bounds__(256, 3) void attn_kernel(
    const __bf16* __restrict__ Q, const __bf16* __restrict__ K,
    const __bf16* __restrict__ Vt,
    __bf16* __restrict__ po, float* __restrict__ pm, float* __restrict__ pl,
    __bf16* __restrict__ Ob, int ks) {
    __shared__ __align__(16) __bf16 Ks[3][32 * 128];
    __shared__ __align__(16) __bf16 Vs[3][128 * 32];
    const int lane = threadIdx.x & 63, wv = threadIdx.x >> 6;   // wv 0..3
    const int l32 = lane & 31, hi = lane >> 5;
    // grid: 8 xcd x 3 bh_l x (16 tiles x ks)  -> bh pinned to XCD
    const int id  = blockIdx.x;
    const int xcd = id & 7;
    const int idx = id >> 3;
    const int bh_l = idx % 3, rem = idx / 3;
    const int c = rem % ks, tl = rem / ks;                      // tl 0..15
    const int tile = (tl & 1) ? (15 - (tl >> 1)) : (tl >> 1);   // heavy/light mix
    const int bh = xcd + 8 * bh_l;
    const int b = bh / HEADS, h = bh - b * HEADS;
    const int qw0 = tile * 128 + wv * 32;                       // wave's first q row
    const float qs = 0.12751674770951932f;  // 1/sqrt(128) * log2(e)

    // Q B-frags: col=q=lane&31, k = 8*hi + e, 8 chunks over D=128
    bf16x8 qfr[8];
    {
        const __bf16* qp = Q + (size_t)(b*SEQ + qw0 + l32) * DIM + h*HDIM + hi*8;
#pragma unroll
        for (int cc = 0; cc < 8; ++cc) {
            bf16x8 v = *(const bf16x8*)(qp + cc*16);
            bf16x8 sv;
#pragma unroll
            for (int e = 0; e < 8; ++e) sv[e] = (__bf16)((float)v[e] * qs);
            qfr[cc] = sv;
        }
    }

    const __bf16* kgb = K  + (size_t)(b*SEQ) * DIM + h*HDIM;
    const __bf16* vgb = Vt + (size_t)bh * HDIM * SEQ;

    // stage one k-block: K 32x128 (8 instrs) + V 128x32 (8 instrs), 4/wave
    auto stage = [&](int buf, int kb) {
        const int kbase = kb * 32;
#pragma unroll
        for (int s = 0; s < 2; ++s) {
            const int j = wv * 2 + s;              // 0..7, wave-uniform
            const int row = j * 4 + (lane >> 4);
            const int c16 = (lane & 15) ^ (row & 7);
            const __bf16* gp = kgb + (size_t)(kbase + row) * DIM + c16 * 8;
            __builtin_amdgcn_global_load_lds((const gbl_v*)gp,
                (lds_v*)&Ks[buf][j * 512], 16, 0, 0);
        }
#pragma unroll
        for (int s = 0; s < 2; ++s) {
            const int j = wv * 2 + s;              // 0..7, wave-uniform
            const int row = j * 16 + (lane >> 2);  // d-row 0..127
            const int c4 = (lane & 3) ^ ((row >> 1) & 3);
            const __bf16* gp = vgb + (size_t)row * SEQ + kbase + c4 * 8;
            __builtin_amdgcn_global_load_lds((const gbl_v*)gp,
                (lds_v*)&Vs[buf][j * 512], 16, 0, 0);
        }
    };

    f32x16 o[4] = {};                          // O^T accum: 4 d-blocks of 32
    float mx = -INFINITY, lsum = 0.f;
    const int nkb = min(4 * tile + 5, NKV);
    const int cnt = (nkb - c + ks - 1) / ks;

    stage(0, c);
    for (int i = 0; i < cnt; ++i) {
        const int kb = c + i * ks;
        const int kbase = kb * 32;
        const int cur = i % 3;
        if (i + 1 < cnt) {
            stage((i + 1) % 3, kb + ks);
            asm volatile("s_waitcnt vmcnt(4)" ::: "memory");   // stage(i) landed
        } else {
            asm volatile("s_waitcnt vmcnt(0)" ::: "memory");
        }
        __builtin_amdgcn_s_barrier();          // all waves' stage(i) published

        if (kbase <= qw0 + 32) {               // wave-uniform activity test
            // QK^T: A = K from LDS (row=key=l32, k=8hi+e), B = Q
            f32x16 s = {};
            __builtin_amdgcn_s_setprio(1);
#pragma unroll
            for (int cc = 0; cc < 8; ++cc) {
                const int c8 = ((cc << 1) | hi) ^ (l32 & 7);   // swizzled slot
                bf16x8 kf = *(const bf16x8*)&Ks[cur][l32 * 128 + c8 * 8];
                s = mfma32(kf, qfr[cc], s);
            }
            __builtin_amdgcn_s_setprio(0);
            // V A-frags from LDS: row=d=db*32+l32, chunk u=kc*2+hi swizzled
            bf16x8 vf[8];
#pragma unroll
            for (int db = 0; db < 4; ++db)
#pragma unroll
                for (int kc = 0; kc < 2; ++kc) {
                    const int row = db * 32 + l32;
                    const int u = ((kc*2 + hi) ^ ((row >> 1) & 3));
                    vf[db*2 + kc] = *(const bf16x8*)&Vs[cur][row * 32 + u * 8];
                }

            float p[16];
#pragma unroll
            for (int r = 0; r < 16; ++r) p[r] = s[r];
            if (kbase + 30 > qw0) {            // diagonal: apply causal mask
                const int q1 = qw0 + l32 + 1;
#pragma unroll
                for (int r = 0; r < 16; ++r) {
                    const int key = kbase + (r & 3) + 8*(r >> 2) + 4*hi;
                    if (key > q1) p[r] = -INFINITY;
                }
            }
            float m0 = p[0];
#pragma unroll
            for (int r = 1; r < 16; ++r) m0 = fmaxf(m0, p[r]);
            m0 = fmaxf(m0, __shfl_xor(m0, 32));
            // defer-max: skip rescale while growth <= 8 (log2 domain)
            const bool defer = __all(m0 <= mx + 8.f && mx > -3e38f);
            if (!defer) {
                const float mnew = fmaxf(mx, m0);
                const float resc = (mx < mnew) ? exp2f(mx - mnew) : 1.0f;
                lsum *= resc;
#pragma unroll
                for (int db = 0; db < 4; ++db)
#pragma unroll
                    for (int r = 0; r < 16; ++r) o[db][r] *= resc;
                mx = mnew;
            }
            const float mref = (mx == -INFINITY) ? 0.f : mx;   // all-masked guard
#pragma unroll
            for (int r = 0; r < 16; ++r) p[r] = exp2f(p[r] - mref);
            float rs = 0.f;
#pragma unroll
            for (int r = 0; r < 16; ++r) rs += p[r];
            rs += __shfl_xor(rs, 32);
            lsum += rs;
            // P -> bf16 B-frags via cvt_pk + permlane32_swap
            union { unsigned int u[4]; bf16x8 v; } pw[2];
#pragma unroll
            for (int kc = 0; kc < 2; ++kc) {
                unsigned int X = cvtpk(p[8*kc + 0], p[8*kc + 1]);
                unsigned int Y = cvtpk(p[8*kc + 4], p[8*kc + 5]);
                asm("v_permlane32_swap_b32 %0, %1" : "+v"(X), "+v"(Y));
                unsigned int X2 = cvtpk(p[8*kc + 2], p[8*kc + 3]);
                unsigned int Y2 = cvtpk(p[8*kc + 6], p[8*kc + 7]);
                asm("v_permlane32_swap_b32 %0, %1" : "+v"(X2), "+v"(Y2));
                pw[kc].u[0] = X; pw[kc].u[1] = X2; pw[kc].u[2] = Y; pw[kc].u[3] = Y2;
            }
            __builtin_amdgcn_s_setprio(1);
#pragma unroll
            for (int db = 0; db < 4; ++db) {
                o[db] = mfma32(vf[db*2 + 0], pw[0].v, o[db]);
                o[db] = mfma32(vf[db*2 + 1], pw[1].v, o[db]);
            }
            __builtin_amdgcn_s_setprio(0);
        }
    }

    // write-out: lane holds q = qw0+l32 (col), d = db*32 + (reg&3)+8*(reg>>2)+4*hi
    if (ks == 1) {
        const float inv = 1.0f / lsum;
        __bf16* op = Ob + (size_t)(b*SEQ + qw0 + l32) * DIM + h*HDIM + hi*4;
#pragma unroll
        for (int db = 0; db < 4; ++db)
#pragma unroll
            for (int g = 0; g < 4; ++g) {
                bf16x4 pk;
#pragma unroll
                for (int r = 0; r < 4; ++r) pk[r] = (__bf16)(o[db][g*4 + r] * inv);
                *(bf16x4*)(op + db*32 + g*8) = pk;
            }
    } else {
        const int pid = (bh * 16 + tile) * ks + c;
        const int lq  = wv * 32 + l32;         // 0..127
        __bf16* pop = po + ((size_t)pid * 128 + lq) * HDIM + hi*4;
#pragma unroll
        for (int db = 0; db < 4; ++db)
#pragma unroll
            for (int g = 0; g < 4; ++g) {
                bf16x4 pk;
#pragma unroll
                for (int r = 0; r < 4; ++r) pk[r] = (__bf16)o[db][g*4 + r];
                *(bf16x4*)(pop + db*32 + g*8) = pk;
            }
        if (hi == 0) {
            pm[(size_t)pid * 128 + lq] = mx;
            pl[(size_t)pid * 128 + lq] = lsum;
        }
    }
}

// ---------------- merge split-K partials (128-row tiles) ----------------
__global__ __launch_bounds__(256) void merge_kernel(const __bf16* __restrict__ po,
    const float* __restrict__ pm, const float* __restrict__ pl,
    __bf16* __restrict__ Ob, int ks) {
    const int id = blockIdx.x;             // bh*16 + tile
    const int bh = id >> 4, tile = id & 15;
    const int b = bh / HEADS, h = bh - b * HEADS;
    const int lq = threadIdx.x >> 1;       // 0..127
    const int d0 = (threadIdx.x & 1) * 64;
    const int pb = id * ks;
    float M = -INFINITY;
    for (int cc = 0; cc < ks; ++cc) M = fmaxf(M, pm[(size_t)(pb + cc) * 128 + lq]);
    float L = 0.f, w[2] = {0.f, 0.f};
    for (int cc = 0; cc < ks; ++cc) {
        w[cc] = exp2f(pm[(size_t)(pb + cc) * 128 + lq] - M);
        L += w[cc] * pl[(size_t)(pb + cc) * 128 + lq];
    }
    const float invL = 1.0f / L;
    __bf16* op = Ob + (size_t)(b*SEQ + tile*128 + lq) * DIM + h*HDIM;
#pragma unroll
    for (int d = 0; d < 64; d += 8) {
        float acc[8] = {};
        for (int cc = 0; cc < ks; ++cc) {
            bf16x8 v = *(const bf16x8*)&po[((size_t)(pb + cc) * 128 + lq) * HDIM + d0 + d];
            const float wc = w[cc];
#pragma unroll
            for (int e = 0; e < 8; ++e) acc[e] += wc * (float)v[e];
        }
        bf16x8 ov;
#pragma unroll
        for (int e = 0; e < 8; ++e) ov[e] = (__bf16)(acc[e] * invL);
        *(bf16x8*)(op + d0 + d) = ov;
    }
}

// ---------------- launch ----------------
extern "C" void kernel_launch(void* const* d_in, const int* in_sizes, int n_in,
                              void* d_out, int out_size, void* d_ws, size_t ws_size,
                              hipStream_t stream) {
    const float* x  = (const float*)d_in[0];
    const float* Wq = (const float*)d_in[1];
    const float* bq = (const float*)d_in[2];
    const float* Wk = (const float*)d_in[3];
    const float* bk = (const float*)d_in[4];
    const float* Wv = (const float*)d_in[5];
    const float* bv = (const float*)d_in[6];
    const float* Wo = (const float*)d_in[7];
    const float* bo = (const float*)d_in[8];

    char* p = (char*)d_ws;
    const size_t SZ_X = (size_t)MTOT * DIM * 2;        // 12.6 MB
    const size_t SZ_W = (size_t)DIM * DIM * 2;         // 1.18 MB
    __bf16* xb   = (__bf16*)p; p += SZ_X;
    __bf16* Wcat = (__bf16*)p; p += 3 * SZ_W;          // [2304][768]
    __bf16* Wto  = (__bf16*)p; p += SZ_W;
    __bf16* Qb   = (__bf16*)p; p += SZ_X;
    __bf16* Kb   = (__bf16*)p; p += SZ_X;
    __bf16* Vt   = (__bf16*)p; p += SZ_X;
    __bf16* Ob   = (__bf16*)p; p += SZ_X;

    const size_t base = (size_t)(p - (char*)d_ws);
    const size_t SZ_PO = (size_t)24 * 16 * 2 * 128 * HDIM * 2;  // 25.2 MB (ks=2)
    const size_t SZ_PM = (size_t)24 * 16 * 2 * 128 * 4;         // 0.39 MB
    const int ks = (ws_size >= base + SZ_PO + 2 * SZ_PM) ? 2 : 1;
    __bf16* po = (__bf16*)p;            p += SZ_PO;
    float*  pmv = (float*)p;            p += SZ_PM;
    float*  plv = (float*)p;

    cast_x_kernel<<<(MTOT * DIM) / 1024, 256, 0, stream>>>(x, xb);
    transpose_w_kernel<<<dim3(DIM/32, DIM/32, 4), 256, 0, stream>>>(
        Wq, Wk, Wv, Wo,
        Wcat, Wcat + (size_t)DIM*DIM, Wcat + (size_t)2*DIM*DIM, Wto);

    gemm_qkv<<<(MTOT/128) * (2304/128), 256, 0, stream>>>(xb, Wcat, bq, bk, bv, Qb, Kb, Vt);

    attn_kernel<<<8 * 3 * 16 * ks, 256, 0, stream>>>(Qb, Kb, Vt, po, pmv, plv, Ob, ks);
    if (ks == 2)
        merge_kernel<<<24 * 16, 256, 0, stream>>>(po, pmv, plv, Ob, ks);

    gemm_out<<<(MTOT/128) * (DIM/128), 256, 0, stream>>>(Ob, Wto, bo, (float*)d_out);
}